// Round 7
// baseline (799.431 us; speedup 1.0000x reference)
//
#include <hip/hip_runtime.h>

#define BS   16
#define NMEM 256
#define NQ   63
#define T    64          // NQ + 1
#define D    512
#define H    512
#define G4   2048        // 4*H

#define K2C  2.885390081777927f   // 2*log2(e)

typedef __attribute__((ext_vector_type(8))) short short8;
typedef __attribute__((ext_vector_type(4))) float float4v;
typedef __attribute__((ext_vector_type(4))) unsigned int uint4v;

// ---------------- workspace layout (float offsets) ----------------
enum : size_t {
    OFF_XW  = 0,                            // [T][BS][G4]
    OFF_YS  = OFF_XW  + (size_t)T*BS*G4,    // [T+1][BS][H]  (fp32, b-major, for q-gemm)
    OFF_HB  = OFF_YS  + (size_t)(T+1)*BS*H, // [T+1][2][8192] bf16 hi/lo
    OFF_AF  = OFF_HB  + (size_t)(T+1)*BS*H, // [BS][NMEM][H]
    OFF_Q   = OFF_AF  + (size_t)BS*NMEM*H,  // [T][BS][H]
    OFF_X   = OFF_Q   + (size_t)T*BS*H,     // [T][BS][D]
    OFF_B   = OFF_X   + (size_t)T*BS*D,     // [G4]
};

__device__ inline unsigned short bf16_rn(float x) {
    union { float f; unsigned u; } a; a.f = x;
    unsigned r = a.u + 0x7FFFu + ((a.u >> 16) & 1u);
    return (unsigned short)(r >> 16);
}
__device__ inline float bf16_to_f(unsigned short s) {
    union { float f; unsigned u; } a; a.u = ((unsigned)s) << 16;
    return a.f;
}

// ---------------- prep: build x, bias, hbuf[0], canary hbuf[1..T] ----------------
// Canary 0x7FFF (bf16 NaN) is unreachable by real hi/lo planes (bf16_rn of
// finite tanh outputs / residuals never yields 0x7FFF) -> payload-poll barrier.
__global__ void prep(const float* __restrict__ lstm_in, const float* __restrict__ init_h,
                     const float* __restrict__ init_i,
                     const float* __restrict__ b_ih, const float* __restrict__ b_hh,
                     float* __restrict__ xbuf, float* __restrict__ biasbuf,
                     unsigned short* __restrict__ hb0)
{
    int i = blockIdx.x * blockDim.x + threadIdx.x;
    const int NX = T*BS*D;
    const int CAN0 = NX + G4 + 8192;
    if (i < NX) {
        int d = i & 511; int r = i >> 9; int t = r >> 4; int b = r & 15;
        float v = (t == 0) ? init_i[d] : lstm_in[((size_t)(b*NQ) + (t-1))*D + d];
        __builtin_nontemporal_store(v, xbuf + i);
    } else if (i < NX + G4) {
        int j = i - NX; biasbuf[j] = b_ih[j] + b_hh[j];
    } else if (i < CAN0) {
        int e = i - (NX + G4);
        int iw = e & 7;
        int k = ((e >> 3) >> 4) * 8 + iw;
        float h0 = init_h[k];
        unsigned short hi = bf16_rn(h0);
        unsigned short lo = bf16_rn(h0 - bf16_to_f(hi));
        hb0[e] = hi;
        hb0[8192 + e] = lo;
    } else if (i < CAN0 + T*8192) {
        // poison hbuf[1..T] (T slots x 16384 shorts = T*8192 dwords)
        ((unsigned*)hb0)[8192 + (i - CAN0)] = 0x7FFF7FFFu;
    }
}

// ---------------- split-bf16 MFMA GEMM unit ----------------
// 256 threads compute a 64x64 C tile of A[M,K] @ op(B), fp32 in/out.
// BT=true: B is [N,K] (C = A*B^T). BT=false: B is [K,N].
// C = Ah*Bh + Al*Bh + Ah*Bl (split-bf16, ~2^-16 relative).
template<bool BT>
__device__ inline void gemm_unit(const float* __restrict__ A, const float* __restrict__ B,
                                 float* __restrict__ C, const float* __restrict__ bias,
                                 int N, int K, int tm, int tn, int t2)
{
    const int w = t2 >> 6, lane = t2 & 63;
    const int quad = lane >> 4, l15 = lane & 15;
    const int am = tm + w*16 + l15;
    float4v acch[4] = {{0,0,0,0},{0,0,0,0},{0,0,0,0},{0,0,0,0}};
    float4v accl[4] = {{0,0,0,0},{0,0,0,0},{0,0,0,0},{0,0,0,0}};
    for (int k0 = 0; k0 < K; k0 += 32) {
        const float* ap = A + (size_t)am*K + k0 + quad*8;
        float4 a0 = *(const float4*)ap, a1 = *(const float4*)(ap+4);
        float av[8] = {a0.x,a0.y,a0.z,a0.w,a1.x,a1.y,a1.z,a1.w};
        short8 ah, al;
#pragma unroll
        for (int i = 0; i < 8; ++i) {
            unsigned short hi = bf16_rn(av[i]);
            ah[i] = (short)hi; al[i] = (short)bf16_rn(av[i] - bf16_to_f(hi));
        }
#pragma unroll
        for (int ni = 0; ni < 4; ++ni) {
            const int n = tn + ni*16 + l15;
            float bv[8];
            if (BT) {
                const float* bp = B + (size_t)n*K + k0 + quad*8;
                float4 b0 = *(const float4*)bp, b1 = *(const float4*)(bp+4);
                bv[0]=b0.x; bv[1]=b0.y; bv[2]=b0.z; bv[3]=b0.w;
                bv[4]=b1.x; bv[5]=b1.y; bv[6]=b1.z; bv[7]=b1.w;
            } else {
                const float* bp = B + (size_t)(k0 + quad*8)*N + n;
#pragma unroll
                for (int i = 0; i < 8; ++i) bv[i] = bp[(size_t)i*N];
            }
            short8 bh, bl;
#pragma unroll
            for (int i = 0; i < 8; ++i) {
                unsigned short hi = bf16_rn(bv[i]);
                bh[i] = (short)hi; bl[i] = (short)bf16_rn(bv[i] - bf16_to_f(hi));
            }
            acch[ni] = __builtin_amdgcn_mfma_f32_16x16x32_bf16(ah, bh, acch[ni], 0, 0, 0);
            accl[ni] = __builtin_amdgcn_mfma_f32_16x16x32_bf16(al, bh, accl[ni], 0, 0, 0);
            accl[ni] = __builtin_amdgcn_mfma_f32_16x16x32_bf16(ah, bl, accl[ni], 0, 0, 0);
        }
    }
#pragma unroll
    for (int ni = 0; ni < 4; ++ni) {
        const int n = tn + ni*16 + l15;
        float bb = bias ? bias[n] : 0.f;
        float4v r = acch[ni] + accl[ni];
#pragma unroll
        for (int j = 0; j < 4; ++j) {
            int row = tm + w*16 + quad*4 + j;
            __builtin_nontemporal_store(r[j] + bb, C + (size_t)row*N + n);
        }
    }
}

template<bool BT>
__global__ __launch_bounds__(256) void gemm_mfma(const float* __restrict__ A,
                                                 const float* __restrict__ B,
                                                 float* __restrict__ C,
                                                 const float* __restrict__ bias,
                                                 int N, int K)
{
    gemm_unit<BT>(A, B, C, bias, N, K, blockIdx.y*64, blockIdx.x*64, threadIdx.x);
}

// ---------------- persistent LSTM (blocks 0-31) + fused af GEMM (blocks 32-287) ----
// barrier v7: NO flags. prep poisons hbuf[1..T] with 0x7FFF canaries; consumers
// re-issue their sc0sc1 h-fragment loads until canary-free. The payload IS the
// barrier: removes the per-step store-drain AND the flag hop (2 of 3 IF$ RTs).
// part/xwb double-buffered by t&1 -> single __syncthreads per step.
// Deadlock-free by construction: producers are co-grid blocks, no scope tricks,
// stale-data replay passes instantly.
__global__ __launch_bounds__(512, 2) void lstm_af(
    const float* __restrict__ xW,        // [T][BS][G4]
    const float* __restrict__ w_hh,      // [G4][H]
    const float* __restrict__ init_c,    // [H]
    const float* __restrict__ ks,        // [BS*NMEM][D]
    const float* __restrict__ wm,        // [D][H]
    float* __restrict__ ys,              // [T+1][BS][H]
    unsigned short* __restrict__ hbuf,   // [T+1][2][8192]
    float* __restrict__ af)              // [BS*NMEM][H]
{
    const int tid = threadIdx.x;

    if (blockIdx.x >= 32) {
        // ---------- fused af = ks @ wm (split-bf16 MFMA, no LDS, no barriers) ------
        const int u = tid >> 8;                    // two 256-thr units per block
        const int tau = (blockIdx.x - 32)*2 + u;   // 0..511 tiles: M=4096/64 x N=512/64
        gemm_unit<false>(ks, wm, af, nullptr, H, D, (tau >> 3)*64, (tau & 7)*64, tid & 255);
        return;
    }

    // ---------- LSTM recurrence ----------
    __shared__ float smem[6144];
    float* part = smem;              // [2][8][64][4]
    float* xwb  = smem + 4096;       // [2][4][16][16]  (parity, gate, b, j16)

    const int jt    = blockIdx.x;
    const int w     = tid >> 6;
    const int g     = w >> 1;
    const int khalf = w & 1;
    const int lane  = tid & 63;
    const int quad  = lane >> 4;
    const int l15   = lane & 15;

    // one-time weight preload -> bf16 hi/lo B-fragments in VGPRs
    short8 bh[8], bl[8];
    {
        const int row = g*512 + jt*16 + l15;
        const float* wr = w_hh + (size_t)row*H + khalf*256 + quad*8;
#pragma unroll
        for (int kt = 0; kt < 8; ++kt) {
            const float* wp = wr + kt*32;
#pragma unroll
            for (int i = 0; i < 8; ++i) {
                float v = wp[i];
                unsigned short hi = bf16_rn(v);
                bh[kt][i] = (short)hi;
                bl[kt][i] = (short)bf16_rn(v - bf16_to_f(hi));
            }
        }
    }

    const int b2 = tid >> 4, j16 = tid & 15;       // finalize mapping (tid<256)
    float creg = 0.f;
    if (tid < 256) creg = init_c[jt*16 + j16];     // c-state in a register
    if (tid >= 256) {                              // stage xW[0] -> LDS parity 0
        int ti = tid - 256;
        int bb = ti >> 4, s = ti & 15;
        int gg = s & 3, j4 = (s >> 2) << 2;
        float4 v = *(const float4*)(xW + (size_t)bb*G4 + gg*512 + jt*16 + j4);
        float* dst = xwb + gg*256 + bb*16 + j4;
        dst[0]=v.x; dst[1]=v.y; dst[2]=v.z; dst[3]=v.w;
    }
    __syncthreads();

    for (int t = 0; t < T; ++t) {
        // ---- poll-load h_t fragments (sc0 sc1, IF$) until canary-free ----
        const unsigned short* hbt = hbuf + (size_t)t*16384;
        short8 ah[8], al[8];
        bool ok;
        do {
#pragma unroll
            for (int kt = 0; kt < 8; ++kt) {
                int c = ((khalf*8 + kt)*4 + quad)*16 + l15;
                const unsigned short* p0 = hbt + (size_t)c*8;
                const unsigned short* p1 = p0 + 8192;
                asm volatile("global_load_dwordx4 %0, %1, off sc0 sc1"
                             : "=v"(ah[kt]) : "v"(p0) : "memory");
                asm volatile("global_load_dwordx4 %0, %1, off sc0 sc1"
                             : "=v"(al[kt]) : "v"(p1) : "memory");
            }
            asm volatile("s_waitcnt vmcnt(0)" ::: "memory");
            __builtin_amdgcn_sched_barrier(0);   // rule #18: checks stay below wait
            ok = true;
#pragma unroll
            for (int kt = 0; kt < 8; ++kt) {
                uint4v u0, u1;
                __builtin_memcpy(&u0, &ah[kt], 16);
                __builtin_memcpy(&u1, &al[kt], 16);
#pragma unroll
                for (int d2 = 0; d2 < 4; ++d2) {
                    ok = ok && ((u0[d2] & 0xFFFFu) != 0x7FFFu) && ((u0[d2] >> 16) != 0x7FFFu);
                    ok = ok && ((u1[d2] & 0xFFFFu) != 0x7FFFu) && ((u1[d2] >> 16) != 0x7FFFu);
                }
            }
        } while (!ok);
        __builtin_amdgcn_sched_barrier(0);       // MFMAs stay below final wait

        // ---- split-bf16 MFMA ----
        float4v a0 = {0.f,0.f,0.f,0.f}, a1 = {0.f,0.f,0.f,0.f};
#pragma unroll
        for (int kt = 0; kt < 8; ++kt) {
            a0 = __builtin_amdgcn_mfma_f32_16x16x32_bf16(ah[kt], bh[kt], a0, 0, 0, 0);
            a1 = __builtin_amdgcn_mfma_f32_16x16x32_bf16(al[kt], bh[kt], a1, 0, 0, 0);
            a1 = __builtin_amdgcn_mfma_f32_16x16x32_bf16(ah[kt], bl[kt], a1, 0, 0, 0);
        }
        a0 += a1;
        *(float4v*)&part[(t&1)*2048 + (w*64 + lane)*4] = a0;  // m(b)=quad*4+reg, n(j)=lane&15
        __syncthreads();   // A: part[par(t)] complete before finalize reads

        // ---- finalize: 256 threads = (b2, j16); fire-and-forget h stores ----
        if (tid < 256) {
            const int pb = (t&1)*2048, xb0 = (t&1)*1024;
            const int lsrc = ((b2 >> 2)*16 + j16)*4, r = b2 & 3;
            float gi = part[pb + 0*256 + lsrc + r] + part[pb + 1*256 + lsrc + r] + xwb[xb0 + 0*256 + b2*16 + j16];
            float gf = part[pb + 2*256 + lsrc + r] + part[pb + 3*256 + lsrc + r] + xwb[xb0 + 1*256 + b2*16 + j16];
            float gg = part[pb + 4*256 + lsrc + r] + part[pb + 5*256 + lsrc + r] + xwb[xb0 + 2*256 + b2*16 + j16];
            float go = part[pb + 6*256 + lsrc + r] + part[pb + 7*256 + lsrc + r] + xwb[xb0 + 3*256 + b2*16 + j16];
            float si = 1.f/(1.f+__expf(-gi));
            float sf = 1.f/(1.f+__expf(-gf));
            float so = 1.f/(1.f+__expf(-go));
            float cn = sf*creg + si*tanhf(gg);
            float hn = so*tanhf(cn);
            creg = cn;
            __builtin_nontemporal_store(hn, ys + (size_t)(t+1)*BS*H + b2*H + jt*16 + j16);
            const int k = jt*16 + j16;
            const int e = ((k >> 3)*16 + b2)*8 + (k & 7);
            unsigned short hi = bf16_rn(hn);
            unsigned int hv = (unsigned int)hi;
            unsigned int lv = (unsigned int)bf16_rn(hn - bf16_to_f(hi));
            unsigned short* hb1 = hbuf + (size_t)(t+1)*16384;
            // write-through to IF$; consumers' canary poll IS the ack (no drain)
            asm volatile("global_store_short %0, %1, off sc0 sc1"
                         :: "v"(hb1 + e), "v"(hv) : "memory");
            asm volatile("global_store_short %0, %1, off sc0 sc1"
                         :: "v"(hb1 + 8192 + e), "v"(lv) : "memory");
        }
        if (t < T-1 && tid >= 256) {             // stage xW[t+1] -> parity t+1
            int ti = tid - 256;
            int bb = ti >> 4, s = ti & 15;
            int gg2 = s & 3, j4 = (s >> 2) << 2;
            float4 v = *(const float4*)(xW + (size_t)(t+1)*BS*G4 + bb*G4 + gg2*512 + jt*16 + j4);
            float* dst = xwb + ((t+1)&1)*1024 + gg2*256 + bb*16 + j4;
            dst[0]=v.x; dst[1]=v.y; dst[2]=v.z; dst[3]=v.w;
        }
        // no second barrier: part/xwb are parity-buffered; next sync A orders all
    }
}

// ---------------- fused attention: score[b,t,m] = sum_h tanh(af+q)*v ----------------
__global__ __launch_bounds__(256) void attn(const float* __restrict__ af,
                                            const float* __restrict__ q,
                                            const float* __restrict__ v,
                                            float* __restrict__ out)
{
    __shared__ float afs[64][68];
    __shared__ float qs[4][516];
    __shared__ float vs[512];
    const int tid = threadIdx.x;
    const int mc = blockIdx.x, tc = blockIdx.y, b = blockIdx.z;
    for (int i = tid; i < 4*128; i += 256) {
        int t = i >> 7, h4 = (i & 127) << 2;
        float4 x = *(const float4*)(q + ((size_t)((tc*4 + t)*16 + b) << 9) + h4);
        x.x *= K2C; x.y *= K2C; x.z *= K2C; x.w *= K2C;
        *(float4*)&qs[t][h4] = x;
    }
    for (int i = tid; i < 128; i += 256)
        *(float4*)&vs[i << 2] = *(const float4*)(v + (i << 2));
    const int ml = tid & 63, tg = tid >> 6;
    float acc = 0.f;
    for (int hc = 0; hc < 8; ++hc) {
        __syncthreads();
        for (int i = tid; i < 64*16; i += 256) {
            int m = i >> 4, h4 = (i & 15) << 2;
            float4 x = *(const float4*)(af + ((size_t)(b*NMEM + mc*64 + m) << 9) + hc*64 + h4);
            x.x *= K2C; x.y *= K2C; x.z *= K2C; x.w *= K2C;
            *(float4*)&afs[m][h4] = x;
        }
        __syncthreads();
#pragma unroll
        for (int h8 = 0; h8 < 8; ++h8) {
            float4 a0 = *(const float4*)&afs[ml][h8*8 + 0];
            float4 a1 = *(const float4*)&afs[ml][h8*8 + 4];
            float4 v0 = *(const float4*)&vs[hc*64 + h8*8 + 0];
            float4 v1 = *(const float4*)&vs[hc*64 + h8*8 + 4];
            float4 q0 = *(const float4*)&qs[tg][hc*64 + h8*8 + 0];
            float4 q1 = *(const float4*)&qs[tg][hc*64 + h8*8 + 4];
            const float* ap0 = (const float*)&a0; const float* ap1 = (const float*)&a1;
            const float* vp0 = (const float*)&v0; const float* vp1 = (const float*)&v1;
            const float* qp0 = (const float*)&q0; const float* qp1 = (const float*)&q1;
            float s = acc;
#pragma unroll
            for (int j = 0; j < 4; ++j) {
                float e = exp2f(ap0[j] + qp0[j]);
                s = fmaf(vp0[j], __builtin_amdgcn_rcpf(e + 1.f), s);
            }
#pragma unroll
            for (int j = 0; j < 4; ++j) {
                float e = exp2f(ap1[j] + qp1[j]);
                s = fmaf(vp1[j], __builtin_amdgcn_rcpf(e + 1.f), s);
            }
            acc = s;
        }
    }
    float Sv = 0.f;
    for (int i = 0; i < 512; i += 4) {
        float4 t4 = *(const float4*)&vs[i];
        Sv += t4.x + t4.y + t4.z + t4.w;
    }
    out[((size_t)b*T + tc*4 + tg)*NMEM + mc*64 + ml] = Sv - 2.f*acc;
}

extern "C" void kernel_launch(void* const* d_in, const int* in_sizes, int n_in,
                              void* d_out, int out_size, void* d_ws, size_t ws_size,
                              hipStream_t stream)
{
    const float* ks      = (const float*)d_in[0];
    const float* lstm_in = (const float*)d_in[2];
    const float* init_h  = (const float*)d_in[3];
    const float* init_c  = (const float*)d_in[4];
    const float* init_i  = (const float*)d_in[5];
    const float* w_ih    = (const float*)d_in[6];
    const float* w_hh    = (const float*)d_in[7];
    const float* b_ih    = (const float*)d_in[8];
    const float* b_hh    = (const float*)d_in[9];
    const float* wm      = (const float*)d_in[10];
    const float* wq      = (const float*)d_in[11];
    const float* av      = (const float*)d_in[12];

    float* ws   = (float*)d_ws;
    float* xW   = ws + OFF_XW;
    float* ys   = ws + OFF_YS;
    unsigned short* hbuf = (unsigned short*)(ws + OFF_HB);
    float* af   = ws + OFF_AF;
    float* qb   = ws + OFF_Q;
    float* xb   = ws + OFF_X;
    float* bias = ws + OFF_B;

    const int prep_n = T*BS*D + G4 + 8192 + T*8192;
    prep<<<(prep_n + 255)/256, 256, 0, stream>>>(lstm_in, init_h, init_i,
                                                 b_ih, b_hh, xb, bias, hbuf);
    // xW[1024,2048] = x @ w_ih^T + bias   (split-bf16 MFMA)
    gemm_mfma<true><<<dim3(32, 16), 256, 0, stream>>>(xb, w_ih, xW, bias, G4, D);
    // LSTM recurrence (blocks 0-31, canary-poll barrier) + af = ks @ wm (32-287)
    lstm_af<<<288, 512, 0, stream>>>(xW, w_hh, init_c, ks, wm, ys, hbuf, af);
    // qb[1024,512] = ys[1..64] @ wq       (split-bf16 MFMA)
    gemm_mfma<false><<<dim3(8, 16), 256, 0, stream>>>(ys + BS*H, wq, qb, nullptr, H, H);
    attn<<<dim3(4, 16, 16), 256, 0, stream>>>(af, qb, av, (float*)d_out);
}

// Round 11
// 501.588 us; speedup vs baseline: 1.5938x; 1.5938x over previous
//
#include <hip/hip_runtime.h>

#define BS   16
#define NMEM 256
#define NQ   63
#define T    64          // NQ + 1
#define D    512
#define H    512
#define G4   2048        // 4*H

#define K2C  2.885390081777927f   // 2*log2(e)

#define SPIN_STEP (1u<<20)   // bounded spins: convert any deadlock into a
#define SPIN_JOIN (1u<<22)   // completed-but-wrong run (absmax fail), never a hang

typedef __attribute__((ext_vector_type(8))) short short8;
typedef __attribute__((ext_vector_type(4))) float float4v;

// ---------------- workspace layout (float offsets) ----------------
enum : size_t {
    OFF_XW  = 0,                            // [T][BS][G4]
    OFF_YS  = OFF_XW  + (size_t)T*BS*G4,    // [T+1][BS][H]  (fp32, b-major)
    OFF_HB  = OFF_YS  + (size_t)(T+1)*BS*H, // [T+1][2][8192] bf16 hi/lo
    OFF_AF  = OFF_HB  + (size_t)(T+1)*BS*H, // [BS][NMEM][H]
    OFF_Q   = OFF_AF  + (size_t)BS*NMEM*H,  // (unused, layout stability)
    OFF_X   = OFF_Q   + (size_t)T*BS*H,     // [T][BS][D]
    OFF_B   = OFF_X   + (size_t)T*BS*D,     // [G4]
    OFF_BAR = OFF_B   + (size_t)G4,         // 768 ints: 32 step flags stride16; afcnt@512
};

__device__ inline unsigned short bf16_rn(float x) {
    union { float f; unsigned u; } a; a.f = x;
    unsigned r = a.u + 0x7FFFu + ((a.u >> 16) & 1u);
    return (unsigned short)(r >> 16);
}
__device__ inline float bf16_to_f(unsigned short s) {
    union { float f; unsigned u; } a; a.u = ((unsigned)s) << 16;
    return a.f;
}

// ---------------- prep: build x, bias, hbuf[0] (v5) ----------------
__global__ void prep(const float* __restrict__ lstm_in, const float* __restrict__ init_h,
                     const float* __restrict__ init_i,
                     const float* __restrict__ b_ih, const float* __restrict__ b_hh,
                     float* __restrict__ xbuf, float* __restrict__ biasbuf,
                     unsigned short* __restrict__ hb0)
{
    int i = blockIdx.x * blockDim.x + threadIdx.x;
    const int NX = T*BS*D;
    if (i < NX) {
        int d = i & 511; int r = i >> 9; int t = r >> 4; int b = r & 15;
        float v = (t == 0) ? init_i[d] : lstm_in[((size_t)(b*NQ) + (t-1))*D + d];
        __builtin_nontemporal_store(v, xbuf + i);
    } else if (i < NX + G4) {
        int j = i - NX; biasbuf[j] = b_ih[j] + b_hh[j];
    } else if (i < NX + G4 + 8192) {
        int e = i - (NX + G4);
        int iw = e & 7;
        int k = ((e >> 3) >> 4) * 8 + iw;
        float h0 = init_h[k];
        unsigned short hi = bf16_rn(h0);
        unsigned short lo = bf16_rn(h0 - bf16_to_f(hi));
        hb0[e] = hi;
        hb0[8192 + e] = lo;
    }
}

// ---------------- split-bf16 MFMA GEMM unit (unchanged) ----------------
template<bool BT>
__device__ inline void gemm_unit(const float* __restrict__ A, const float* __restrict__ B,
                                 float* __restrict__ C, const float* __restrict__ bias,
                                 int N, int K, int tm, int tn, int t2)
{
    const int w = t2 >> 6, lane = t2 & 63;
    const int quad = lane >> 4, l15 = lane & 15;
    const int am = tm + w*16 + l15;
    float4v acch[4] = {{0,0,0,0},{0,0,0,0},{0,0,0,0},{0,0,0,0}};
    float4v accl[4] = {{0,0,0,0},{0,0,0,0},{0,0,0,0},{0,0,0,0}};
    for (int k0 = 0; k0 < K; k0 += 32) {
        const float* ap = A + (size_t)am*K + k0 + quad*8;
        float4 a0 = *(const float4*)ap, a1 = *(const float4*)(ap+4);
        float av[8] = {a0.x,a0.y,a0.z,a0.w,a1.x,a1.y,a1.z,a1.w};
        short8 ah, al;
#pragma unroll
        for (int i = 0; i < 8; ++i) {
            unsigned short hi = bf16_rn(av[i]);
            ah[i] = (short)hi; al[i] = (short)bf16_rn(av[i] - bf16_to_f(hi));
        }
#pragma unroll
        for (int ni = 0; ni < 4; ++ni) {
            const int n = tn + ni*16 + l15;
            float bv[8];
            if (BT) {
                const float* bp = B + (size_t)n*K + k0 + quad*8;
                float4 b0 = *(const float4*)bp, b1 = *(const float4*)(bp+4);
                bv[0]=b0.x; bv[1]=b0.y; bv[2]=b0.z; bv[3]=b0.w;
                bv[4]=b1.x; bv[5]=b1.y; bv[6]=b1.z; bv[7]=b1.w;
            } else {
                const float* bp = B + (size_t)(k0 + quad*8)*N + n;
#pragma unroll
                for (int i = 0; i < 8; ++i) bv[i] = bp[(size_t)i*N];
            }
            short8 bh, bl;
#pragma unroll
            for (int i = 0; i < 8; ++i) {
                unsigned short hi = bf16_rn(bv[i]);
                bh[i] = (short)hi; bl[i] = (short)bf16_rn(bv[i] - bf16_to_f(hi));
            }
            acch[ni] = __builtin_amdgcn_mfma_f32_16x16x32_bf16(ah, bh, acch[ni], 0, 0, 0);
            accl[ni] = __builtin_amdgcn_mfma_f32_16x16x32_bf16(al, bh, accl[ni], 0, 0, 0);
            accl[ni] = __builtin_amdgcn_mfma_f32_16x16x32_bf16(ah, bl, accl[ni], 0, 0, 0);
        }
    }
#pragma unroll
    for (int ni = 0; ni < 4; ++ni) {
        const int n = tn + ni*16 + l15;
        float bb = bias ? bias[n] : 0.f;
        float4v r = acch[ni] + accl[ni];
#pragma unroll
        for (int j = 0; j < 4; ++j) {
            int row = tm + w*16 + quad*4 + j;
            __builtin_nontemporal_store(r[j] + bb, C + (size_t)row*N + n);
        }
    }
}

template<bool BT>
__global__ __launch_bounds__(256) void gemm_mfma(const float* __restrict__ A,
                                                 const float* __restrict__ B,
                                                 float* __restrict__ C,
                                                 const float* __restrict__ bias,
                                                 int N, int K)
{
    gemm_unit<BT>(A, B, C, bias, N, K, blockIdx.y*64, blockIdx.x*64, threadIdx.x);
}

// ------- persistent kernel: LSTM (blocks 0-31, v5 sc0sc1 flag barrier, NO fences)
//         + workers (32-287): af GEMM -> one-time join -> wait flags -> q + attn ---
// All waits are BOUNDED (SPIN_*): a latent deadlock becomes a completed-but-wrong
// run (absmax fail + counters) instead of a dead container.
__global__ __launch_bounds__(512, 2) void lstm_af(
    const float* __restrict__ xW,        // [T][BS][G4]
    const float* __restrict__ w_hh,      // [G4][H]
    const float* __restrict__ init_c,    // [H]
    const float* __restrict__ ks,        // [BS*NMEM][D]
    const float* __restrict__ wm,        // [D][H]
    const float* __restrict__ wq,        // [H][H]
    const float* __restrict__ av,        // [H]
    float* __restrict__ ys,              // [T+1][BS][H]
    unsigned short* __restrict__ hbuf,   // [T+1][2][8192]
    float* __restrict__ af,              // [BS*NMEM][H]
    float* __restrict__ out,             // [BS][T][NMEM]
    int* __restrict__ flags)             // 32 step flags stride16; afcnt@512
{
    const int tid = threadIdx.x;
    __shared__ float smem[13328];
    // worker: afs0@0[64][68], afs1@4352, qs@8704[4][516], vs@10768[512], ysb@11280[4][512]
    // lstm:   part@0[8][64][4], cst@2048[16][16], xwb@2304[4][16][16]

    if (blockIdx.x >= 32) {
        // ================= worker =================
        const int wkr = blockIdx.x - 32;           // 0..255
        const int u   = tid >> 8;                  // unit 0/1
        const int t2  = tid & 255;

        // ---- phase 1: af = ks @ wm tile ----
        const int tau = wkr*2 + u;                 // 512 tiles: M=4096/64 x N=512/64
        gemm_unit<false>(ks, wm, af, nullptr, H, D, (tau >> 3)*64, (tau & 7)*64, t2);

        // ---- one-time af join (release-add / acquire-fence), bounded ----
        asm volatile("s_waitcnt vmcnt(0)" ::: "memory");   // own af stores acked
        __syncthreads();
        if (tid == 0) {
            __hip_atomic_fetch_add(&flags[512], 1, __ATOMIC_RELEASE,
                                   __HIP_MEMORY_SCOPE_AGENT);   // wbl2: flush af
            int c; unsigned spin = 0;
            do {
                c = __hip_atomic_load(&flags[512], __ATOMIC_RELAXED,
                                      __HIP_MEMORY_SCOPE_AGENT);
            } while (c < 256 && ++spin < SPIN_JOIN);
        }
        __syncthreads();
        __builtin_amdgcn_fence(__ATOMIC_ACQUIRE, "agent"); // inv: af reads fresh

        // ---- phase 2: wait ys rows for this tc (v5 sc0sc1 poll, bounded) ----
        const int tc = wkr & 15, b = wkr >> 4;
        const int tneed = tc*4 + 4;                // need ys rows 1..tc*4+4
        if (tid < 64) {
            const int fidx = (tid & 31) << 4;
            const int* fp = flags + fidx;
            int v; unsigned spin = 0;
            do {
                asm volatile("global_load_dword %0, %1, off sc0 sc1\n\t"
                             "s_waitcnt vmcnt(0)"
                             : "=v"(v) : "v"(fp) : "memory");
            } while (!__all(v >= tneed) && ++spin < SPIN_STEP);
        }
        __syncthreads();

        float* afs0 = smem;
        float* afs1 = smem + 4352;
        float* qs   = smem + 8704;      // [4][516]
        float* vs   = smem + 10768;     // [512]
        float* ysb  = smem + 11280;     // [4][512]

        // stage ys rows (tc*4+1+t, b), t=0..3 via sc0sc1 (IF$-fresh)
        {
            float yv0, yv1, yv2, yv3;
            const float* y0p = ys + (((size_t)(tc*4 + 1)*16) + b)*512 + tid;
            const float* y1p = y0p + (size_t)16*512;
            const float* y2p = y1p + (size_t)16*512;
            const float* y3p = y2p + (size_t)16*512;
            asm volatile("global_load_dword %0, %1, off sc0 sc1" : "=v"(yv0) : "v"(y0p) : "memory");
            asm volatile("global_load_dword %0, %1, off sc0 sc1" : "=v"(yv1) : "v"(y1p) : "memory");
            asm volatile("global_load_dword %0, %1, off sc0 sc1" : "=v"(yv2) : "v"(y2p) : "memory");
            asm volatile("global_load_dword %0, %1, off sc0 sc1" : "=v"(yv3) : "v"(y3p) : "memory");
            asm volatile("s_waitcnt vmcnt(0)" ::: "memory");
            __builtin_amdgcn_sched_barrier(0);
            ysb[0*512 + tid] = yv0; ysb[1*512 + tid] = yv1;
            ysb[2*512 + tid] = yv2; ysb[3*512 + tid] = yv3;
        }
        vs[tid & 511] = av[tid & 511];
        __syncthreads();

        // q[t][tid] = sum_k ysb[t][k] * wq[k][tid]  (coalesced wq row reads)
        {
            float q0=0.f, q1=0.f, q2=0.f, q3=0.f;
            for (int k = 0; k < 512; ++k) {
                float wv = wq[(size_t)k*512 + tid];
                float y0 = ysb[k], y1 = ysb[512+k], y2 = ysb[1024+k], y3 = ysb[1536+k];
                q0 = fmaf(y0, wv, q0); q1 = fmaf(y1, wv, q1);
                q2 = fmaf(y2, wv, q2); q3 = fmaf(y3, wv, q3);
            }
            qs[0*516 + tid] = q0*K2C; qs[1*516 + tid] = q1*K2C;
            qs[2*516 + tid] = q2*K2C; qs[3*516 + tid] = q3*K2C;
        }
        __syncthreads();

        float Sv = 0.f;
        for (int i = 0; i < 512; i += 4) {
            float4 t4 = *(const float4*)&vs[i];
            Sv += t4.x + t4.y + t4.z + t4.w;
        }

        float* afs_u = u ? afs1 : afs0;
        const int ml = t2 & 63, tg = t2 >> 6;
#pragma unroll
        for (int mcidx = 0; mcidx < 2; ++mcidx) {
            const int mc = u + mcidx*2;            // unit0: {0,2}, unit1: {1,3}
            float acc = 0.f;
            for (int hc = 0; hc < 8; ++hc) {
                __syncthreads();
                for (int i = t2; i < 64*16; i += 256) {
                    int m = i >> 4, h4 = (i & 15) << 2;
                    float4 x = *(const float4*)(af + ((size_t)(b*NMEM + mc*64 + m) << 9) + hc*64 + h4);
                    x.x *= K2C; x.y *= K2C; x.z *= K2C; x.w *= K2C;
                    *(float4*)&afs_u[m*68 + h4] = x;
                }
                __syncthreads();
#pragma unroll
                for (int h8 = 0; h8 < 8; ++h8) {
                    float4 a0 = *(const float4*)&afs_u[ml*68 + h8*8 + 0];
                    float4 a1 = *(const float4*)&afs_u[ml*68 + h8*8 + 4];
                    float4 v0 = *(const float4*)&vs[hc*64 + h8*8 + 0];
                    float4 v1 = *(const float4*)&vs[hc*64 + h8*8 + 4];
                    float4 q0 = *(const float4*)&qs[tg*516 + hc*64 + h8*8 + 0];
                    float4 q1 = *(const float4*)&qs[tg*516 + hc*64 + h8*8 + 4];
                    const float* ap0 = (const float*)&a0; const float* ap1 = (const float*)&a1;
                    const float* vp0 = (const float*)&v0; const float* vp1 = (const float*)&v1;
                    const float* qp0 = (const float*)&q0; const float* qp1 = (const float*)&q1;
                    float s = acc;
#pragma unroll
                    for (int j = 0; j < 4; ++j) {
                        float e = exp2f(ap0[j] + qp0[j]);
                        s = fmaf(vp0[j], __builtin_amdgcn_rcpf(e + 1.f), s);
                    }
#pragma unroll
                    for (int j = 0; j < 4; ++j) {
                        float e = exp2f(ap1[j] + qp1[j]);
                        s = fmaf(vp1[j], __builtin_amdgcn_rcpf(e + 1.f), s);
                    }
                    acc = s;
                }
            }
            out[((size_t)b*T + tc*4 + tg)*NMEM + mc*64 + ml] = Sv - 2.f*acc;
        }
        return;
    }

    // ================= LSTM recurrence (v5 verbatim; flags released every step) ====
    float* part = smem;              // [8][64][4]
    float* cst  = smem + 2048;       // [16][16]
    float* xwb  = smem + 2304;       // [4][16][16]

    const int jt    = blockIdx.x;
    const int w     = tid >> 6;
    const int g     = w >> 1;
    const int khalf = w & 1;
    const int lane  = tid & 63;
    const int quad  = lane >> 4;
    const int l15   = lane & 15;

    short8 bh[8], bl[8];
    {
        const int row = g*512 + jt*16 + l15;
        const float* wr = w_hh + (size_t)row*H + khalf*256 + quad*8;
#pragma unroll
        for (int kt = 0; kt < 8; ++kt) {
            const float* wp = wr + kt*32;
#pragma unroll
            for (int i = 0; i < 8; ++i) {
                float v = wp[i];
                unsigned short hi = bf16_rn(v);
                bh[kt][i] = (short)hi;
                bl[kt][i] = (short)bf16_rn(v - bf16_to_f(hi));
            }
        }
    }

    const int b2 = tid >> 4, j16 = tid & 15;
    if (tid < 256) cst[b2*16 + j16] = init_c[jt*16 + j16];
    if (tid >= 256) {
        int ti = tid - 256;
        int bb = ti >> 4, s = ti & 15;
        int gg = s & 3, j4 = (s >> 2) << 2;
        float4 v = *(const float4*)(xW + (size_t)bb*G4 + gg*512 + jt*16 + j4);
        float* dst = xwb + gg*256 + bb*16 + j4;
        dst[0]=v.x; dst[1]=v.y; dst[2]=v.z; dst[3]=v.w;
    }
    __syncthreads();

    for (int t = 0; t < T; ++t) {
        const unsigned short* hbt = hbuf + (size_t)t*16384;
        short8 ah[8], al[8];
#pragma unroll
        for (int kt = 0; kt < 8; ++kt) {
            int c = ((khalf*8 + kt)*4 + quad)*16 + l15;
            const unsigned short* p0 = hbt + (size_t)c*8;
            const unsigned short* p1 = p0 + 8192;
            asm volatile("global_load_dwordx4 %0, %1, off sc0 sc1"
                         : "=v"(ah[kt]) : "v"(p0) : "memory");
            asm volatile("global_load_dwordx4 %0, %1, off sc0 sc1"
                         : "=v"(al[kt]) : "v"(p1) : "memory");
        }
        asm volatile("s_waitcnt vmcnt(0)" ::: "memory");
        __builtin_amdgcn_sched_barrier(0);

        float4v a0 = {0.f,0.f,0.f,0.f}, a1 = {0.f,0.f,0.f,0.f};
#pragma unroll
        for (int kt = 0; kt < 8; ++kt) {
            a0 = __builtin_amdgcn_mfma_f32_16x16x32_bf16(ah[kt], bh[kt], a0, 0, 0, 0);
            a1 = __builtin_amdgcn_mfma_f32_16x16x32_bf16(al[kt], bh[kt], a1, 0, 0, 0);
            a1 = __builtin_amdgcn_mfma_f32_16x16x32_bf16(ah[kt], bl[kt], a1, 0, 0, 0);
        }
        a0 += a1;
        *(float4v*)&part[(w*64 + lane)*4] = a0;
        __syncthreads();

        if (tid < 256) {
            const int lsrc = ((b2 >> 2)*16 + j16)*4, r = b2 & 3;
            float gi = part[(0*256) + lsrc + r] + part[(1*256) + lsrc + r] + xwb[0*256 + b2*16 + j16];
            float gf = part[(2*256) + lsrc + r] + part[(3*256) + lsrc + r] + xwb[1*256 + b2*16 + j16];
            float gg = part[(4*256) + lsrc + r] + part[(5*256) + lsrc + r] + xwb[2*256 + b2*16 + j16];
            float go = part[(6*256) + lsrc + r] + part[(7*256) + lsrc + r] + xwb[3*256 + b2*16 + j16];
            float si = 1.f/(1.f+__expf(-gi));
            float sf = 1.f/(1.f+__expf(-gf));
            float so = 1.f/(1.f+__expf(-go));
            float cn = sf*cst[b2*16 + j16] + si*tanhf(gg);
            float hn = so*tanhf(cn);
            cst[b2*16 + j16] = cn;
            // ys via sc0sc1 write-through: IF$-visible for same-kernel workers
            const float* ysp = ys + (size_t)(t+1)*BS*H + b2*H + jt*16 + j16;
            asm volatile("global_store_dword %0, %1, off sc0 sc1"
                         :: "v"(ysp), "v"(hn) : "memory");
            const int k = jt*16 + j16;
            const int e = ((k >> 3)*16 + b2)*8 + (k & 7);
            unsigned short hi = bf16_rn(hn);
            unsigned int hv = (unsigned int)hi;
            unsigned int lv = (unsigned int)bf16_rn(hn - bf16_to_f(hi));
            unsigned short* hb1 = hbuf + (size_t)(t+1)*16384;
            asm volatile("global_store_short %0, %1, off sc0 sc1"
                         :: "v"(hb1 + e), "v"(hv) : "memory");
            asm volatile("global_store_short %0, %1, off sc0 sc1"
                         :: "v"(hb1 + 8192 + e), "v"(lv) : "memory");
            asm volatile("s_waitcnt vmcnt(0)" ::: "memory");   // payload at IF$
        }
        __syncthreads();

        // release flags=t+1 every step (incl. t=T-1: publishes ys[T] to workers)
        if (tid == 0) {
            int fv = t + 1;
            asm volatile("global_store_dword %0, %1, off sc0 sc1"
                         :: "v"(flags + jt*16), "v"(fv) : "memory");
        }
        if (t < T-1) {
            if (tid >= 256) {                       // stage xW[t+1] under the wait
                int ti = tid - 256;
                int bb = ti >> 4, s = ti & 15;
                int gg2 = s & 3, j4 = (s >> 2) << 2;
                float4 v = *(const float4*)(xW + (size_t)(t+1)*BS*G4 + bb*G4 + gg2*512 + jt*16 + j4);
                float* dst = xwb + gg2*256 + bb*16 + j4;
                dst[0]=v.x; dst[1]=v.y; dst[2]=v.z; dst[3]=v.w;
            }
            if (tid < 64) {                         // wave-parallel poll, bounded
                const int fidx = (tid & 31) << 4;
                const int* fp = flags + fidx;
                int v; unsigned spin = 0;
                do {
                    asm volatile("global_load_dword %0, %1, off sc0 sc1\n\t"
                                 "s_waitcnt vmcnt(0)"
                                 : "=v"(v) : "v"(fp) : "memory");
                } while (!__all(v >= t+1) && ++spin < SPIN_STEP);
            }
            __syncthreads();
        }
    }
}

extern "C" void kernel_launch(void* const* d_in, const int* in_sizes, int n_in,
                              void* d_out, int out_size, void* d_ws, size_t ws_size,
                              hipStream_t stream)
{
    const float* ks      = (const float*)d_in[0];
    const float* lstm_in = (const float*)d_in[2];
    const float* init_h  = (const float*)d_in[3];
    const float* init_c  = (const float*)d_in[4];
    const float* init_i  = (const float*)d_in[5];
    const float* w_ih    = (const float*)d_in[6];
    const float* w_hh    = (const float*)d_in[7];
    const float* b_ih    = (const float*)d_in[8];
    const float* b_hh    = (const float*)d_in[9];
    const float* wm      = (const float*)d_in[10];
    const float* wq      = (const float*)d_in[11];
    const float* av      = (const float*)d_in[12];

    float* ws   = (float*)d_ws;
    float* xW   = ws + OFF_XW;
    float* ys   = ws + OFF_YS;
    unsigned short* hbuf = (unsigned short*)(ws + OFF_HB);
    float* af   = ws + OFF_AF;
    float* xb   = ws + OFF_X;
    float* bias = ws + OFF_B;
    int*   flags= (int*)(ws + OFF_BAR);

    hipMemsetAsync(flags, 0, 768*sizeof(int), stream);

    const int prep_n = T*BS*D + G4 + 8192;
    prep<<<(prep_n + 255)/256, 256, 0, stream>>>(lstm_in, init_h, init_i,
                                                 b_ih, b_hh, xb, bias, hbuf);
    // xW[1024,2048] = x @ w_ih^T + bias   (split-bf16 MFMA)
    gemm_mfma<true><<<dim3(32, 16), 256, 0, stream>>>(xb, w_ih, xW, bias, G4, D);
    // LSTM (blocks 0-31) + workers: af GEMM -> join -> per-(tc,b) q + attn -> out
    lstm_af<<<288, 512, 0, stream>>>(xW, w_hh, init_c, ks, wm, wq, av,
                                     ys, hbuf, af, (float*)d_out, flags);
}

// Round 15
// 485.402 us; speedup vs baseline: 1.6469x; 1.0333x over previous
//
#include <hip/hip_runtime.h>

#define BS   16
#define NMEM 256
#define NQ   63
#define T    64          // NQ + 1
#define D    512
#define H    512
#define G4   2048        // 4*H

#define K2C  2.885390081777927f   // 2*log2(e)

#define SPIN_STEP (1u<<20)   // LSTM tight poll cap
#define SPIN_SLOW (1u<<16)   // worker backoff poll cap (~260ms at 4us/round)

typedef __attribute__((ext_vector_type(8))) short short8;
typedef __attribute__((ext_vector_type(4))) float float4v;

// ---------------- workspace layout (float offsets) ----------------
enum : size_t {
    OFF_XW  = 0,                            // [T][BS][G4]
    OFF_YS  = OFF_XW  + (size_t)T*BS*G4,    // [T+1][BS][H]  (fp32, b-major)
    OFF_HB  = OFF_YS  + (size_t)(T+1)*BS*H, // [T+1][2][8192] bf16 hi/lo
    OFF_AF  = OFF_HB  + (size_t)(T+1)*BS*H, // [BS][NMEM][H]
    OFF_Q   = OFF_AF  + (size_t)BS*NMEM*H,  // (unused, layout stability)
    OFF_X   = OFF_Q   + (size_t)T*BS*H,     // [T][BS][D]
    OFF_B   = OFF_X   + (size_t)T*BS*D,     // [G4]
    OFF_BAR = OFF_B   + (size_t)G4,         // 768 ints: 32 step flags stride16; afcnt@512
};

__device__ inline unsigned short bf16_rn(float x) {
    union { float f; unsigned u; } a; a.f = x;
    unsigned r = a.u + 0x7FFFu + ((a.u >> 16) & 1u);
    return (unsigned short)(r >> 16);
}
__device__ inline float bf16_to_f(unsigned short s) {
    union { float f; unsigned u; } a; a.u = ((unsigned)s) << 16;
    return a.f;
}

// ---------------- prep: build x, bias, hbuf[0] (v5) ----------------
__global__ void prep(const float* __restrict__ lstm_in, const float* __restrict__ init_h,
                     const float* __restrict__ init_i,
                     const float* __restrict__ b_ih, const float* __restrict__ b_hh,
                     float* __restrict__ xbuf, float* __restrict__ biasbuf,
                     unsigned short* __restrict__ hb0)
{
    int i = blockIdx.x * blockDim.x + threadIdx.x;
    const int NX = T*BS*D;
    if (i < NX) {
        int d = i & 511; int r = i >> 9; int t = r >> 4; int b = r & 15;
        float v = (t == 0) ? init_i[d] : lstm_in[((size_t)(b*NQ) + (t-1))*D + d];
        __builtin_nontemporal_store(v, xbuf + i);
    } else if (i < NX + G4) {
        int j = i - NX; biasbuf[j] = b_ih[j] + b_hh[j];
    } else if (i < NX + G4 + 8192) {
        int e = i - (NX + G4);
        int iw = e & 7;
        int k = ((e >> 3) >> 4) * 8 + iw;
        float h0 = init_h[k];
        unsigned short hi = bf16_rn(h0);
        unsigned short lo = bf16_rn(h0 - bf16_to_f(hi));
        hb0[e] = hi;
        hb0[8192 + e] = lo;
    }
}

// ---------------- split-bf16 MFMA GEMM unit (unchanged) ----------------
template<bool BT>
__device__ inline void gemm_unit(const float* __restrict__ A, const float* __restrict__ B,
                                 float* __restrict__ C, const float* __restrict__ bias,
                                 int N, int K, int tm, int tn, int t2)
{
    const int w = t2 >> 6, lane = t2 & 63;
    const int quad = lane >> 4, l15 = lane & 15;
    const int am = tm + w*16 + l15;
    float4v acch[4] = {{0,0,0,0},{0,0,0,0},{0,0,0,0},{0,0,0,0}};
    float4v accl[4] = {{0,0,0,0},{0,0,0,0},{0,0,0,0},{0,0,0,0}};
    for (int k0 = 0; k0 < K; k0 += 32) {
        const float* ap = A + (size_t)am*K + k0 + quad*8;
        float4 a0 = *(const float4*)ap, a1 = *(const float4*)(ap+4);
        float av[8] = {a0.x,a0.y,a0.z,a0.w,a1.x,a1.y,a1.z,a1.w};
        short8 ah, al;
#pragma unroll
        for (int i = 0; i < 8; ++i) {
            unsigned short hi = bf16_rn(av[i]);
            ah[i] = (short)hi; al[i] = (short)bf16_rn(av[i] - bf16_to_f(hi));
        }
#pragma unroll
        for (int ni = 0; ni < 4; ++ni) {
            const int n = tn + ni*16 + l15;
            float bv[8];
            if (BT) {
                const float* bp = B + (size_t)n*K + k0 + quad*8;
                float4 b0 = *(const float4*)bp, b1 = *(const float4*)(bp+4);
                bv[0]=b0.x; bv[1]=b0.y; bv[2]=b0.z; bv[3]=b0.w;
                bv[4]=b1.x; bv[5]=b1.y; bv[6]=b1.z; bv[7]=b1.w;
            } else {
                const float* bp = B + (size_t)(k0 + quad*8)*N + n;
#pragma unroll
                for (int i = 0; i < 8; ++i) bv[i] = bp[(size_t)i*N];
            }
            short8 bh, bl;
#pragma unroll
            for (int i = 0; i < 8; ++i) {
                unsigned short hi = bf16_rn(bv[i]);
                bh[i] = (short)hi; bl[i] = (short)bf16_rn(bv[i] - bf16_to_f(hi));
            }
            acch[ni] = __builtin_amdgcn_mfma_f32_16x16x32_bf16(ah, bh, acch[ni], 0, 0, 0);
            accl[ni] = __builtin_amdgcn_mfma_f32_16x16x32_bf16(al, bh, accl[ni], 0, 0, 0);
            accl[ni] = __builtin_amdgcn_mfma_f32_16x16x32_bf16(ah, bl, accl[ni], 0, 0, 0);
        }
    }
#pragma unroll
    for (int ni = 0; ni < 4; ++ni) {
        const int n = tn + ni*16 + l15;
        float bb = bias ? bias[n] : 0.f;
        float4v r = acch[ni] + accl[ni];
#pragma unroll
        for (int j = 0; j < 4; ++j) {
            int row = tm + w*16 + quad*4 + j;
            __builtin_nontemporal_store(r[j] + bb, C + (size_t)row*N + n);
        }
    }
}

template<bool BT>
__global__ __launch_bounds__(256) void gemm_mfma(const float* __restrict__ A,
                                                 const float* __restrict__ B,
                                                 float* __restrict__ C,
                                                 const float* __restrict__ bias,
                                                 int N, int K)
{
    gemm_unit<BT>(A, B, C, bias, N, K, blockIdx.y*64, blockIdx.x*64, threadIdx.x);
}

// ------- persistent kernel: LSTM (blocks 0-31) + workers (32-287) ---------------
// v12 = v11 (passed, 501us) + s_sleep(127) backoff in BOTH worker poll loops.
// Diagnosis: v11's unthrottled worker polls (256 blks x 64 lanes, tight sc0sc1 +
// vmcnt(0)) hammered the same 32 flag cache lines the LSTM barrier rides on ->
// per-step 3.36 -> 6.1us. Backoff (~4us/round) cuts poll pressure >10x; workers
// have ~13us slack per tc-slice so the late-detect cost is negligible.
__global__ __launch_bounds__(512, 2) void lstm_af(
    const float* __restrict__ xW,        // [T][BS][G4]
    const float* __restrict__ w_hh,      // [G4][H]
    const float* __restrict__ init_c,    // [H]
    const float* __restrict__ ks,        // [BS*NMEM][D]
    const float* __restrict__ wm,        // [D][H]
    const float* __restrict__ wq,        // [H][H]
    const float* __restrict__ av,        // [H]
    float* __restrict__ ys,              // [T+1][BS][H]
    unsigned short* __restrict__ hbuf,   // [T+1][2][8192]
    float* __restrict__ af,              // [BS*NMEM][H]
    float* __restrict__ out,             // [BS][T][NMEM]
    int* __restrict__ flags)             // 32 step flags stride16; afcnt@512
{
    const int tid = threadIdx.x;
    __shared__ float smem[13328];
    // worker: afs0@0[64][68], afs1@4352, qs@8704[4][516], vs@10768[512], ysb@11280[4][512]
    // lstm:   part@0[8][64][4], cst@2048[16][16], xwb@2304[4][16][16]

    if (blockIdx.x >= 32) {
        // ================= worker =================
        const int wkr = blockIdx.x - 32;           // 0..255
        const int u   = tid >> 8;                  // unit 0/1
        const int t2  = tid & 255;

        // ---- phase 1: af = ks @ wm tile ----
        const int tau = wkr*2 + u;                 // 512 tiles: M=4096/64 x N=512/64
        gemm_unit<false>(ks, wm, af, nullptr, H, D, (tau >> 3)*64, (tau & 7)*64, t2);

        // ---- one-time af join (release-add / acquire-fence), backoff poll ----
        asm volatile("s_waitcnt vmcnt(0)" ::: "memory");   // own af stores acked
        __syncthreads();
        if (tid == 0) {
            __hip_atomic_fetch_add(&flags[512], 1, __ATOMIC_RELEASE,
                                   __HIP_MEMORY_SCOPE_AGENT);   // wbl2: flush af
            int c; unsigned spin = 0;
            for (;;) {
                c = __hip_atomic_load(&flags[512], __ATOMIC_RELAXED,
                                      __HIP_MEMORY_SCOPE_AGENT);
                if (c >= 256 || ++spin >= SPIN_SLOW) break;
                __builtin_amdgcn_s_sleep(127);     // ~4us: keep flag lines quiet
            }
        }
        __syncthreads();
        __builtin_amdgcn_fence(__ATOMIC_ACQUIRE, "agent"); // inv: af reads fresh

        // ---- phase 2: wait ys rows for this tc (backoff poll) ----
        const int tc = wkr & 15, b = wkr >> 4;
        const int tneed = tc*4 + 4;                // need ys rows 1..tc*4+4
        if (tid < 64) {
            const int fidx = (tid & 31) << 4;
            const int* fp = flags + fidx;
            int v; unsigned spin = 0;
            for (;;) {
                asm volatile("global_load_dword %0, %1, off sc0 sc1\n\t"
                             "s_waitcnt vmcnt(0)"
                             : "=v"(v) : "v"(fp) : "memory");
                if (__all(v >= tneed) || ++spin >= SPIN_SLOW) break;
                __builtin_amdgcn_s_sleep(127);     // ~4us backoff
            }
        }
        __syncthreads();

        float* afs0 = smem;
        float* afs1 = smem + 4352;
        float* qs   = smem + 8704;      // [4][516]
        float* vs   = smem + 10768;     // [512]
        float* ysb  = smem + 11280;     // [4][512]

        // stage ys rows (tc*4+1+t, b), t=0..3 via sc0sc1 (IF$-fresh)
        {
            float yv0, yv1, yv2, yv3;
            const float* y0p = ys + (((size_t)(tc*4 + 1)*16) + b)*512 + tid;
            const float* y1p = y0p + (size_t)16*512;
            const float* y2p = y1p + (size_t)16*512;
            const float* y3p = y2p + (size_t)16*512;
            asm volatile("global_load_dword %0, %1, off sc0 sc1" : "=v"(yv0) : "v"(y0p) : "memory");
            asm volatile("global_load_dword %0, %1, off sc0 sc1" : "=v"(yv1) : "v"(y1p) : "memory");
            asm volatile("global_load_dword %0, %1, off sc0 sc1" : "=v"(yv2) : "v"(y2p) : "memory");
            asm volatile("global_load_dword %0, %1, off sc0 sc1" : "=v"(yv3) : "v"(y3p) : "memory");
            asm volatile("s_waitcnt vmcnt(0)" ::: "memory");
            __builtin_amdgcn_sched_barrier(0);
            ysb[0*512 + tid] = yv0; ysb[1*512 + tid] = yv1;
            ysb[2*512 + tid] = yv2; ysb[3*512 + tid] = yv3;
        }
        vs[tid & 511] = av[tid & 511];
        __syncthreads();

        // q[t][tid] = sum_k ysb[t][k] * wq[k][tid]  (coalesced wq row reads)
        {
            float q0=0.f, q1=0.f, q2=0.f, q3=0.f;
            for (int k = 0; k < 512; ++k) {
                float wv = wq[(size_t)k*512 + tid];
                float y0 = ysb[k], y1 = ysb[512+k], y2 = ysb[1024+k], y3 = ysb[1536+k];
                q0 = fmaf(y0, wv, q0); q1 = fmaf(y1, wv, q1);
                q2 = fmaf(y2, wv, q2); q3 = fmaf(y3, wv, q3);
            }
            qs[0*516 + tid] = q0*K2C; qs[1*516 + tid] = q1*K2C;
            qs[2*516 + tid] = q2*K2C; qs[3*516 + tid] = q3*K2C;
        }
        __syncthreads();

        float Sv = 0.f;
        for (int i = 0; i < 512; i += 4) {
            float4 t4 = *(const float4*)&vs[i];
            Sv += t4.x + t4.y + t4.z + t4.w;
        }

        float* afs_u = u ? afs1 : afs0;
        const int ml = t2 & 63, tg = t2 >> 6;
#pragma unroll
        for (int mcidx = 0; mcidx < 2; ++mcidx) {
            const int mc = u + mcidx*2;            // unit0: {0,2}, unit1: {1,3}
            float acc = 0.f;
            for (int hc = 0; hc < 8; ++hc) {
                __syncthreads();
                for (int i = t2; i < 64*16; i += 256) {
                    int m = i >> 4, h4 = (i & 15) << 2;
                    float4 x = *(const float4*)(af + ((size_t)(b*NMEM + mc*64 + m) << 9) + hc*64 + h4);
                    x.x *= K2C; x.y *= K2C; x.z *= K2C; x.w *= K2C;
                    *(float4*)&afs_u[m*68 + h4] = x;
                }
                __syncthreads();
#pragma unroll
                for (int h8 = 0; h8 < 8; ++h8) {
                    float4 a0 = *(const float4*)&afs_u[ml*68 + h8*8 + 0];
                    float4 a1 = *(const float4*)&afs_u[ml*68 + h8*8 + 4];
                    float4 v0 = *(const float4*)&vs[hc*64 + h8*8 + 0];
                    float4 v1 = *(const float4*)&vs[hc*64 + h8*8 + 4];
                    float4 q0 = *(const float4*)&qs[tg*516 + hc*64 + h8*8 + 0];
                    float4 q1 = *(const float4*)&qs[tg*516 + hc*64 + h8*8 + 4];
                    const float* ap0 = (const float*)&a0; const float* ap1 = (const float*)&a1;
                    const float* vp0 = (const float*)&v0; const float* vp1 = (const float*)&v1;
                    const float* qp0 = (const float*)&q0; const float* qp1 = (const float*)&q1;
                    float s = acc;
#pragma unroll
                    for (int j = 0; j < 4; ++j) {
                        float e = exp2f(ap0[j] + qp0[j]);
                        s = fmaf(vp0[j], __builtin_amdgcn_rcpf(e + 1.f), s);
                    }
#pragma unroll
                    for (int j = 0; j < 4; ++j) {
                        float e = exp2f(ap1[j] + qp1[j]);
                        s = fmaf(vp1[j], __builtin_amdgcn_rcpf(e + 1.f), s);
                    }
                    acc = s;
                }
            }
            out[((size_t)b*T + tc*4 + tg)*NMEM + mc*64 + ml] = Sv - 2.f*acc;
        }
        return;
    }

    // ================= LSTM recurrence (v5 verbatim; flags released every step) ====
    float* part = smem;              // [8][64][4]
    float* cst  = smem + 2048;       // [16][16]
    float* xwb  = smem + 2304;       // [4][16][16]

    const int jt    = blockIdx.x;
    const int w     = tid >> 6;
    const int g     = w >> 1;
    const int khalf = w & 1;
    const int lane  = tid & 63;
    const int quad  = lane >> 4;
    const int l15   = lane & 15;

    short8 bh[8], bl[8];
    {
        const int row = g*512 + jt*16 + l15;
        const float* wr = w_hh + (size_t)row*H + khalf*256 + quad*8;
#pragma unroll
        for (int kt = 0; kt < 8; ++kt) {
            const float* wp = wr + kt*32;
#pragma unroll
            for (int i = 0; i < 8; ++i) {
                float v = wp[i];
                unsigned short hi = bf16_rn(v);
                bh[kt][i] = (short)hi;
                bl[kt][i] = (short)bf16_rn(v - bf16_to_f(hi));
            }
        }
    }

    const int b2 = tid >> 4, j16 = tid & 15;
    if (tid < 256) cst[b2*16 + j16] = init_c[jt*16 + j16];
    if (tid >= 256) {
        int ti = tid - 256;
        int bb = ti >> 4, s = ti & 15;
        int gg = s & 3, j4 = (s >> 2) << 2;
        float4 v = *(const float4*)(xW + (size_t)bb*G4 + gg*512 + jt*16 + j4);
        float* dst = xwb + gg*256 + bb*16 + j4;
        dst[0]=v.x; dst[1]=v.y; dst[2]=v.z; dst[3]=v.w;
    }
    __syncthreads();

    for (int t = 0; t < T; ++t) {
        const unsigned short* hbt = hbuf + (size_t)t*16384;
        short8 ah[8], al[8];
#pragma unroll
        for (int kt = 0; kt < 8; ++kt) {
            int c = ((khalf*8 + kt)*4 + quad)*16 + l15;
            const unsigned short* p0 = hbt + (size_t)c*8;
            const unsigned short* p1 = p0 + 8192;
            asm volatile("global_load_dwordx4 %0, %1, off sc0 sc1"
                         : "=v"(ah[kt]) : "v"(p0) : "memory");
            asm volatile("global_load_dwordx4 %0, %1, off sc0 sc1"
                         : "=v"(al[kt]) : "v"(p1) : "memory");
        }
        asm volatile("s_waitcnt vmcnt(0)" ::: "memory");
        __builtin_amdgcn_sched_barrier(0);

        float4v a0 = {0.f,0.f,0.f,0.f}, a1 = {0.f,0.f,0.f,0.f};
#pragma unroll
        for (int kt = 0; kt < 8; ++kt) {
            a0 = __builtin_amdgcn_mfma_f32_16x16x32_bf16(ah[kt], bh[kt], a0, 0, 0, 0);
            a1 = __builtin_amdgcn_mfma_f32_16x16x32_bf16(al[kt], bh[kt], a1, 0, 0, 0);
            a1 = __builtin_amdgcn_mfma_f32_16x16x32_bf16(ah[kt], bl[kt], a1, 0, 0, 0);
        }
        a0 += a1;
        *(float4v*)&part[(w*64 + lane)*4] = a0;
        __syncthreads();

        if (tid < 256) {
            const int lsrc = ((b2 >> 2)*16 + j16)*4, r = b2 & 3;
            float gi = part[(0*256) + lsrc + r] + part[(1*256) + lsrc + r] + xwb[0*256 + b2*16 + j16];
            float gf = part[(2*256) + lsrc + r] + part[(3*256) + lsrc + r] + xwb[1*256 + b2*16 + j16];
            float gg = part[(4*256) + lsrc + r] + part[(5*256) + lsrc + r] + xwb[2*256 + b2*16 + j16];
            float go = part[(6*256) + lsrc + r] + part[(7*256) + lsrc + r] + xwb[3*256 + b2*16 + j16];
            float si = 1.f/(1.f+__expf(-gi));
            float sf = 1.f/(1.f+__expf(-gf));
            float so = 1.f/(1.f+__expf(-go));
            float cn = sf*cst[b2*16 + j16] + si*tanhf(gg);
            float hn = so*tanhf(cn);
            cst[b2*16 + j16] = cn;
            // ys via sc0sc1 write-through: IF$-visible for same-kernel workers
            const float* ysp = ys + (size_t)(t+1)*BS*H + b2*H + jt*16 + j16;
            asm volatile("global_store_dword %0, %1, off sc0 sc1"
                         :: "v"(ysp), "v"(hn) : "memory");
            const int k = jt*16 + j16;
            const int e = ((k >> 3)*16 + b2)*8 + (k & 7);
            unsigned short hi = bf16_rn(hn);
            unsigned int hv = (unsigned int)hi;
            unsigned int lv = (unsigned int)bf16_rn(hn - bf16_to_f(hi));
            unsigned short* hb1 = hbuf + (size_t)(t+1)*16384;
            asm volatile("global_store_short %0, %1, off sc0 sc1"
                         :: "v"(hb1 + e), "v"(hv) : "memory");
            asm volatile("global_store_short %0, %1, off sc0 sc1"
                         :: "v"(hb1 + 8192 + e), "v"(lv) : "memory");
            asm volatile("s_waitcnt vmcnt(0)" ::: "memory");   // payload at IF$
        }
        __syncthreads();

        // release flags=t+1 every step (incl. t=T-1: publishes ys[T] to workers)
        if (tid == 0) {
            int fv = t + 1;
            asm volatile("global_store_dword %0, %1, off sc0 sc1"
                         :: "v"(flags + jt*16), "v"(fv) : "memory");
        }
        if (t < T-1) {
            if (tid >= 256) {                       // stage xW[t+1] under the wait
                int ti = tid - 256;
                int bb = ti >> 4, s = ti & 15;
                int gg2 = s & 3, j4 = (s >> 2) << 2;
                float4 v = *(const float4*)(xW + (size_t)(t+1)*BS*G4 + bb*G4 + gg2*512 + jt*16 + j4);
                float* dst = xwb + gg2*256 + bb*16 + j4;
                dst[0]=v.x; dst[1]=v.y; dst[2]=v.z; dst[3]=v.w;
            }
            if (tid < 64) {                         // LSTM poll stays TIGHT (latency-critical)
                const int fidx = (tid & 31) << 4;
                const int* fp = flags + fidx;
                int v; unsigned spin = 0;
                do {
                    asm volatile("global_load_dword %0, %1, off sc0 sc1\n\t"
                                 "s_waitcnt vmcnt(0)"
                                 : "=v"(v) : "v"(fp) : "memory");
                } while (!__all(v >= t+1) && ++spin < SPIN_STEP);
            }
            __syncthreads();
        }
    }
}

extern "C" void kernel_launch(void* const* d_in, const int* in_sizes, int n_in,
                              void* d_out, int out_size, void* d_ws, size_t ws_size,
                              hipStream_t stream)
{
    const float* ks      = (const float*)d_in[0];
    const float* lstm_in = (const float*)d_in[2];
    const float* init_h  = (const float*)d_in[3];
    const float* init_c  = (const float*)d_in[4];
    const float* init_i  = (const float*)d_in[5];
    const float* w_ih    = (const float*)d_in[6];
    const float* w_hh    = (const float*)d_in[7];
    const float* b_ih    = (const float*)d_in[8];
    const float* b_hh    = (const float*)d_in[9];
    const float* wm      = (const float*)d_in[10];
    const float* wq      = (const float*)d_in[11];
    const float* av      = (const float*)d_in[12];

    float* ws   = (float*)d_ws;
    float* xW   = ws + OFF_XW;
    float* ys   = ws + OFF_YS;
    unsigned short* hbuf = (unsigned short*)(ws + OFF_HB);
    float* af   = ws + OFF_AF;
    float* xb   = ws + OFF_X;
    float* bias = ws + OFF_B;
    int*   flags= (int*)(ws + OFF_BAR);

    hipMemsetAsync(flags, 0, 768*sizeof(int), stream);

    const int prep_n = T*BS*D + G4 + 8192;
    prep<<<(prep_n + 255)/256, 256, 0, stream>>>(lstm_in, init_h, init_i,
                                                 b_ih, b_hh, xb, bias, hbuf);
    // xW[1024,2048] = x @ w_ih^T + bias   (split-bf16 MFMA)
    gemm_mfma<true><<<dim3(32, 16), 256, 0, stream>>>(xb, w_ih, xW, bias, G4, D);
    // LSTM (blocks 0-31) + workers: af GEMM -> join -> per-(tc,b) q + attn -> out
    lstm_af<<<288, 512, 0, stream>>>(xW, w_hh, init_c, ks, wm, wq, av,
                                     ys, hbuf, af, (float*)d_out, flags);
}